// Round 3
// baseline (1349.352 us; speedup 1.0000x reference)
//
#include <hip/hip_runtime.h>
#include <math.h>

#define B_N 256
#define T_N 1024
#define D_N 128
#define H_N 256

// LDS map (floats). R0 is triple-purposed (phases are barrier-separated):
//   R0: sX stride 132 (4224) | sAct2 stride 100 (3200) | sAct3 stride 52 (1664)
//   R1: sAct1 stride 100 (3200)
//   accum: 256
#define R0_OFF   0
#define R1_OFF   4224
#define ACC_OFF  7424
#define SMEM_F   7680

__device__ __forceinline__ float sigmoid_f(float z) {
    return 1.0f / (1.0f + __expf(-z));
}

// Dense relu layer, float4 LDS reads. Rows r = tr + 8*i (conflict-free for
// strides {132,100,52}: stride*tr mod 32 spans 8 distinct banks, broadcast
// across tc). K must be a multiple of 4.
template<int K, int N, int NCPT, int INS, int OUTS>
__device__ __forceinline__ void dense_relu(const float* __restrict__ W,
                                           const float* __restrict__ bias,
                                           const float* __restrict__ in,
                                           float* __restrict__ outb,
                                           int tr, int tc)
{
    const int j0 = tc * NCPT;
    if (j0 >= N) return;
    float acc[4][NCPT];
    #pragma unroll
    for (int i = 0; i < 4; ++i)
        #pragma unroll
        for (int c = 0; c < NCPT; ++c) acc[i][c] = 0.0f;

    #pragma unroll 2
    for (int q = 0; q < K / 4; ++q) {
        float a4[4][4];
        #pragma unroll
        for (int i = 0; i < 4; ++i)
            *reinterpret_cast<float4*>(a4[i]) =
                *reinterpret_cast<const float4*>(&in[(tr + 8 * i) * INS + 4 * q]);
        #pragma unroll
        for (int kk = 0; kk < 4; ++kk) {
            float w[NCPT];
            if constexpr (NCPT == 4) {
                const float4 wv = *reinterpret_cast<const float4*>(W + (size_t)(4 * q + kk) * N + j0);
                w[0] = wv.x; w[1] = wv.y; w[2] = wv.z; w[3] = wv.w;
            } else {
                const float2 wv = *reinterpret_cast<const float2*>(W + (size_t)(4 * q + kk) * N + j0);
                w[0] = wv.x; w[1] = wv.y;
            }
            #pragma unroll
            for (int i = 0; i < 4; ++i)
                #pragma unroll
                for (int c = 0; c < NCPT; ++c)
                    acc[i][c] = fmaf(a4[i][kk], w[c], acc[i][c]);
        }
    }
    #pragma unroll
    for (int i = 0; i < 4; ++i) {
        if constexpr (NCPT == 4) {
            float4 o;
            o.x = fmaxf(acc[i][0] + bias[j0 + 0], 0.0f);
            o.y = fmaxf(acc[i][1] + bias[j0 + 1], 0.0f);
            o.z = fmaxf(acc[i][2] + bias[j0 + 2], 0.0f);
            o.w = fmaxf(acc[i][3] + bias[j0 + 3], 0.0f);
            *reinterpret_cast<float4*>(&outb[(tr + 8 * i) * OUTS + j0]) = o;
        } else {
            float2 o;
            o.x = fmaxf(acc[i][0] + bias[j0 + 0], 0.0f);
            o.y = fmaxf(acc[i][1] + bias[j0 + 1], 0.0f);
            *reinterpret_cast<float2*>(&outb[(tr + 8 * i) * OUTS + j0]) = o;
        }
    }
}

// 256->H_N layer fragment: acc += in_region @ W over K (multiple of 4), NCPT=8.
template<int K, int INS>
__device__ __forceinline__ void wide_acc(const float* __restrict__ W,
                                         const float* __restrict__ in,
                                         float (&acc)[4][8], int tr, int j0)
{
    #pragma unroll 2
    for (int q = 0; q < K / 4; ++q) {
        float a4[4][4];
        #pragma unroll
        for (int i = 0; i < 4; ++i)
            *reinterpret_cast<float4*>(a4[i]) =
                *reinterpret_cast<const float4*>(&in[(tr + 8 * i) * INS + 4 * q]);
        #pragma unroll
        for (int kk = 0; kk < 4; ++kk) {
            const float4 w0 = *reinterpret_cast<const float4*>(W + (size_t)(4 * q + kk) * H_N + j0);
            const float4 w1 = *reinterpret_cast<const float4*>(W + (size_t)(4 * q + kk) * H_N + j0 + 4);
            const float w[8] = {w0.x, w0.y, w0.z, w0.w, w1.x, w1.y, w1.z, w1.w};
            #pragma unroll
            for (int i = 0; i < 4; ++i)
                #pragma unroll
                for (int c = 0; c < 8; ++c)
                    acc[i][c] = fmaf(a4[i][kk], w[c], acc[i][c]);
        }
    }
}

// Fused MLP + linearized scan (relu is identity in the scan: gate>0, hidden0=0):
//   hidden[b,h] = sum_t gate[t, b, (h - s*(T-1-t)) mod H]
//   => gate[t][j] scatters to h = (j + s*(T-1-t)) mod H
// Grid: 1024 = 4 t-segments x 256 batch. Block: 256 threads, 8 chunks of 32 t.
__global__ __launch_bounds__(256, 4) void srnn_gate_scan(
    const float* __restrict__ x,
    const float* __restrict__ Wx, const float* __restrict__ bx,
    const float* __restrict__ W1, const float* __restrict__ b1,
    const float* __restrict__ W2, const float* __restrict__ b2,
    const float* __restrict__ W3, const float* __restrict__ b3,
    const float* __restrict__ W4, const float* __restrict__ b4,
    const float* __restrict__ W5, const float* __restrict__ b5,
    const int* __restrict__ shiftp,
    float* __restrict__ out)   // out[0..255]=output, out[256..]=hidden (pre-zeroed)
{
    __shared__ float smem[SMEM_F];
    float* sR0   = smem + R0_OFF;   // sX(132) / sAct2(100) / sAct3(52)
    float* sA1   = smem + R1_OFF;   // stride 100
    float* accum = smem + ACC_OFF;

    const int tid = threadIdx.x;
    const int b   = blockIdx.x & 255;
    const int seg = blockIdx.x >> 8;
    const int tr  = tid & 7;
    const int tc  = tid >> 3;
    const int j0w = tc * 8;         // wide-layer col base
    const int s   = *shiftp;

    accum[tid] = 0.0f;
    __syncthreads();

    for (int chunk = 0; chunk < 8; ++chunk) {
        const int tbase = seg * 256 + chunk * 32;

        // ---- stage 32 x-rows into sR0 (stride 132) ----
        {
            const float* src = x + ((size_t)b * T_N + tbase) * D_N;
            #pragma unroll
            for (int q = 0; q < 4; ++q) {
                int sl = tid + q * 256;          // 1024 float4 slots
                int r  = sl >> 5;
                int c4 = sl & 31;
                float4 v = reinterpret_cast<const float4*>(src)[r * 32 + c4];
                *reinterpret_cast<float4*>(&sR0[r * 132 + c4 * 4]) = v;
            }
        }
        __syncthreads();

        // ---- Lx: 128->256 from sX, keep sigmoided result in regs ----
        float gxs[4][8];
        #pragma unroll
        for (int i = 0; i < 4; ++i)
            #pragma unroll
            for (int c = 0; c < 8; ++c) gxs[i][c] = 0.0f;
        wide_acc<128, 132>(Wx, sR0, gxs, tr, j0w);
        #pragma unroll
        for (int i = 0; i < 4; ++i)
            #pragma unroll
            for (int c = 0; c < 8; ++c)
                gxs[i][c] = sigmoid_f(gxs[i][c] + bx[j0w + c]);

        // ---- L1: sX(132) -> sA1(100) ----
        dense_relu<128, 100, 4, 132, 100>(W1, b1, sR0, sA1, tr, tc);
        __syncthreads();                       // sX dead; sR0 reusable
        // ---- L2: sA1 -> sR0 as sAct2(100) ----
        dense_relu<100, 100, 4, 100, 100>(W2, b2, sA1, sR0, tr, tc);
        __syncthreads();
        // ---- L3: sAct2 -> sA1 ----
        dense_relu<100, 100, 4, 100, 100>(W3, b3, sR0, sA1, tr, tc);
        __syncthreads();
        // ---- L4: sA1 -> sR0 as sAct3(52), N=50 ----
        dense_relu<100,  50, 2, 100,  52>(W4, b4, sA1, sR0, tr, tc);
        __syncthreads();

        // ---- L5: 50->256 from sAct3(52): 48 by quads + 2 remainder ----
        float fx[4][8];
        #pragma unroll
        for (int i = 0; i < 4; ++i)
            #pragma unroll
            for (int c = 0; c < 8; ++c) fx[i][c] = 0.0f;
        wide_acc<48, 52>(W5, sR0, fx, tr, j0w);
        {
            float2 ar[4];
            #pragma unroll
            for (int i = 0; i < 4; ++i)
                ar[i] = *reinterpret_cast<const float2*>(&sR0[(tr + 8 * i) * 52 + 48]);
            #pragma unroll
            for (int kk = 0; kk < 2; ++kk) {
                const float4 w0 = *reinterpret_cast<const float4*>(W5 + (size_t)(48 + kk) * H_N + j0w);
                const float4 w1 = *reinterpret_cast<const float4*>(W5 + (size_t)(48 + kk) * H_N + j0w + 4);
                const float w[8] = {w0.x, w0.y, w0.z, w0.w, w1.x, w1.y, w1.z, w1.w};
                #pragma unroll
                for (int i = 0; i < 4; ++i) {
                    const float a = kk ? ar[i].y : ar[i].x;
                    #pragma unroll
                    for (int c = 0; c < 8; ++c)
                        fx[i][c] = fmaf(a, w[c], fx[i][c]);
                }
            }
        }

        // ---- gate + scatter (linearized scan) ----
        #pragma unroll
        for (int i = 0; i < 4; ++i) {
            const int t    = tbase + tr + 8 * i;
            const int base = s * (T_N - 1 - t);
            #pragma unroll
            for (int c = 0; c < 8; ++c) {
                const float g = sigmoid_f(fx[i][c] + b5[j0w + c]) * gxs[i][c];
                int v = j0w + c + base;
                v = ((v % H_N) + H_N) & (H_N - 1);
                atomicAdd(&accum[v], g);       // per-t the h-map is a bijection
            }
        }
        __syncthreads();                       // protect sR0/accum before next chunk
    }

    // flush partial hidden (4 segment-blocks per b -> global atomic, out zeroed)
    atomicAdd(&out[256 + b * 256 + tid], accum[tid]);
}

// output[b] = sigmoid(hidden[b,:] @ Wo + bo)
__global__ __launch_bounds__(256) void srnn_output(
    const float* __restrict__ Wo, const float* __restrict__ bo,
    float* __restrict__ out)
{
    __shared__ float red[256];
    const int b = blockIdx.x, tid = threadIdx.x;
    red[tid] = out[256 + b * 256 + tid] * Wo[tid];
    __syncthreads();
    #pragma unroll
    for (int off = 128; off > 0; off >>= 1) {
        if (tid < off) red[tid] += red[tid + off];
        __syncthreads();
    }
    if (tid == 0) out[b] = sigmoid_f(red[0] + bo[0]);
}

extern "C" void kernel_launch(void* const* d_in, const int* in_sizes, int n_in,
                              void* d_out, int out_size, void* d_ws, size_t ws_size,
                              hipStream_t stream)
{
    const float* x  = (const float*)d_in[0];
    const float* Wx = (const float*)d_in[1];
    const float* bx = (const float*)d_in[2];
    const float* W1 = (const float*)d_in[3];
    const float* b1 = (const float*)d_in[4];
    const float* W2 = (const float*)d_in[5];
    const float* b2 = (const float*)d_in[6];
    const float* W3 = (const float*)d_in[7];
    const float* b3 = (const float*)d_in[8];
    const float* W4 = (const float*)d_in[9];
    const float* b4 = (const float*)d_in[10];
    const float* W5 = (const float*)d_in[11];
    const float* b5 = (const float*)d_in[12];
    const float* Wo = (const float*)d_in[13];
    const float* bo = (const float*)d_in[14];
    const int* shiftp = (const int*)d_in[15];
    float* out = (float*)d_out;

    // hidden accumulated with atomics -> zero-init (d_out is poisoned)
    hipMemsetAsync(d_out, 0, (size_t)out_size * sizeof(float), stream);

    srnn_gate_scan<<<dim3(1024), dim3(256), 0, stream>>>(
        x, Wx, bx, W1, b1, W2, b2, W3, b3, W4, b4, W5, b5, shiftp, out);
    srnn_output<<<dim3(256), dim3(256), 0, stream>>>(Wo, bo, out);
}

// Round 4
// 891.833 us; speedup vs baseline: 1.5130x; 1.5130x over previous
//
#include <hip/hip_runtime.h>
#include <math.h>

#define B_N 256
#define T_N 1024
#define D_N 128
#define H_N 256

#define LDSX 136          // LDS row stride in bf16 (272 B, 16B-multiple for b128 reads)

typedef __attribute__((ext_vector_type(8))) short short8;   // 8 bf16 = 4 VGPRs
typedef __attribute__((ext_vector_type(4))) float f32x4;

// ws layout (bf16 units): transposed zero-padded weights WT[Npad][Kpad]
#define WXT_OFF 0         // [256][128]
#define W1T_OFF 32768     // [112][128]
#define W2T_OFF 47104     // [112][128]
#define W3T_OFF 61440     // [112][128]
#define W4T_OFF 75776     // [ 64][128]
#define W5T_OFF 83968     // [256][ 64]
#define WT_TOTAL 100352

__device__ __forceinline__ float sigmoid_f(float z) {
    return 1.0f / (1.0f + __expf(-z));
}
__device__ __forceinline__ unsigned short f2bf(float f) {   // RNE fp32->bf16
    unsigned u = __float_as_uint(f);
    return (unsigned short)((u + 0x7FFFu + ((u >> 16) & 1u)) >> 16);
}
__device__ __forceinline__ float bf2f(unsigned short h) {
    return __uint_as_float(((unsigned)h) << 16);
}

// ---- weight prep: fp32 W[K][N] -> bf16 WT[Npad][Kpad] (transposed, zero-padded)
__global__ __launch_bounds__(256) void prep_weights(
    const float* __restrict__ Wx, const float* __restrict__ W1,
    const float* __restrict__ W2, const float* __restrict__ W3,
    const float* __restrict__ W4, const float* __restrict__ W5,
    short* __restrict__ wt)
{
    int idx = blockIdx.x * 256 + threadIdx.x;
    if (idx >= WT_TOTAL) return;
    const float* src; int Kp, K, N, local;
    if (idx < W1T_OFF)      { src = Wx; Kp = 128; K = 128; N = 256; local = idx - WXT_OFF; }
    else if (idx < W2T_OFF) { src = W1; Kp = 128; K = 128; N = 100; local = idx - W1T_OFF; }
    else if (idx < W3T_OFF) { src = W2; Kp = 128; K = 100; N = 100; local = idx - W2T_OFF; }
    else if (idx < W4T_OFF) { src = W3; Kp = 128; K = 100; N = 100; local = idx - W3T_OFF; }
    else if (idx < W5T_OFF) { src = W4; Kp = 128; K = 100; N =  50; local = idx - W4T_OFF; }
    else                    { src = W5; Kp =  64; K =  50; N = 256; local = idx - W5T_OFF; }
    int n = local / Kp, k = local % Kp;
    float v = (k < K && n < N) ? src[(size_t)k * N + n] : 0.0f;
    wt[idx] = (short)f2bf(v);
}

// A-fragment: lane holds A[m=lane&15][k = k0 + (lane>>4)*8 + j], j=0..7
__device__ __forceinline__ short8 ldsA(const short* base, int mbase, int lr, int lq, int k0) {
    return *reinterpret_cast<const short8*>(&base[(mbase + lr) * LDSX + k0 + lq * 8]);
}
// B-fragment: lane holds B[k = k0 + (lane>>4)*8 + j][n = n0 + (lane&15)] from WT[n][k]
__device__ __forceinline__ short8 ldB(const short* wt, int Kp, int n0, int lr, int lq, int k0) {
    return *reinterpret_cast<const short8*>(&wt[(size_t)(n0 + lr) * Kp + k0 + lq * 8]);
}

// Dense layer: NT N-tiles, KS K-steps, relu epilogue, bf16 store (cols >= ncap -> 0).
// C/D layout: row = lq*4 + r, col = n0 + lr  (verified m89/m91).
template<int NT, int KS>
__device__ __forceinline__ void denseL(const short* __restrict__ wt, int Kp,
                                       const float* __restrict__ bias, int ncap,
                                       const short* __restrict__ src, short* __restrict__ dst,
                                       int mbase, int lr, int lq)
{
    short8 a[KS];
    #pragma unroll
    for (int k = 0; k < KS; ++k) a[k] = ldsA(src, mbase, lr, lq, k * 32);
    #pragma unroll 4
    for (int nt = 0; nt < NT; ++nt) {
        const int n0 = nt * 16;
        f32x4 acc = {0.f, 0.f, 0.f, 0.f};
        #pragma unroll
        for (int k = 0; k < KS; ++k)
            acc = __builtin_amdgcn_mfma_f32_16x16x32_bf16(a[k], ldB(wt, Kp, n0, lr, lq, k * 32), acc, 0, 0, 0);
        const int n = n0 + lr;
        const bool valid = (n < ncap);
        const float bv = valid ? bias[n] : 0.0f;
        #pragma unroll
        for (int r = 0; r < 4; ++r) {
            float v = valid ? fmaxf(acc[r] + bv, 0.0f) : 0.0f;
            dst[(mbase + lq * 4 + r) * LDSX + n] = (short)f2bf(v);
        }
    }
}

// Fused MLP + linearized scan (relu is identity in the scan: gate>0, hidden0=0):
//   hidden[b,h] = sum_t gate[t,b,(h - s*(T-1-t)) mod H]  =>  gate[t][j] -> h=(j+s*(T-1-t)) mod H
// 1024 blocks = 4 t-segments x 256 batch. 4 waves/block; wave w owns rows [16w,16w+16)
// of every LDS buffer for the whole chain -> NO barriers in the main loop.
__global__ __launch_bounds__(256, 4) void srnn_gate_scan(
    const float* __restrict__ x, const short* __restrict__ wt,
    const float* __restrict__ bx, const float* __restrict__ b1,
    const float* __restrict__ b2, const float* __restrict__ b3,
    const float* __restrict__ b4, const float* __restrict__ b5,
    const int* __restrict__ shiftp,
    float* __restrict__ out)   // out[0..255]=output, out[256..]=hidden (pre-zeroed)
{
    __shared__ short sbuf[2 * 64 * LDSX];
    short* sX = sbuf;                 // x / L2 out / L4 out
    short* sA = sbuf + 64 * LDSX;     // L1 out / L3 out
    __shared__ float accum[256];

    const int tid = threadIdx.x;
    const int b   = blockIdx.x & 255;
    const int seg = blockIdx.x >> 8;
    const int lane = tid & 63;
    const int w    = tid >> 6;
    const int mbase = w * 16;
    const int lr = lane & 15;         // row-in-tile (A/B n-index); C/D col
    const int lq = lane >> 4;         // quad
    const int s = *shiftp;

    const short* WxT = wt + WXT_OFF;
    const short* W1T = wt + W1T_OFF;
    const short* W2T = wt + W2T_OFF;
    const short* W3T = wt + W3T_OFF;
    const short* W4T = wt + W4T_OFF;
    const short* W5T = wt + W5T_OFF;

    accum[tid] = 0.0f;
    // zero sA cols 112..127 of this wave's rows (L2 runs K=128 over sA; L1/L3 write cols<112)
    {
        uint2 z = {0u, 0u};
        *reinterpret_cast<uint2*>(&sA[(mbase + lr) * LDSX + 112 + lq * 4]) = z;
    }
    __syncthreads();   // accum visible to all waves before any scatter

    for (int rd = 0; rd < 4; ++rd) {
        const int tw0 = seg * 256 + rd * 64 + mbase;   // t of this wave's row 0

        // ---- stage 16 x-rows -> sX bf16 (cols 0..127), wave-local ----
        {
            const float* xsrc = x + ((size_t)b * T_N + tw0) * D_N;
            #pragma unroll
            for (int it = 0; it < 8; ++it) {
                const int row = (lane >> 5) + it * 2;      // 0..15
                const int col = (lane & 31) * 4;
                float4 v = *reinterpret_cast<const float4*>(&xsrc[row * D_N + col]);
                uint2 p;
                p.x = (unsigned)f2bf(v.x) | ((unsigned)f2bf(v.y) << 16);
                p.y = (unsigned)f2bf(v.z) | ((unsigned)f2bf(v.w) << 16);
                *reinterpret_cast<uint2*>(&sX[(mbase + row) * LDSX + col]) = p;
            }
        }

        // ---- Lx: 128->256 from sX; sigmoid; pack bf16 pairs (32 VGPRs) ----
        unsigned gxp[32];
        {
            short8 a0 = ldsA(sX, mbase, lr, lq, 0),  a1 = ldsA(sX, mbase, lr, lq, 32);
            short8 a2 = ldsA(sX, mbase, lr, lq, 64), a3 = ldsA(sX, mbase, lr, lq, 96);
            #pragma unroll 4
            for (int nt = 0; nt < 16; ++nt) {
                const int n0 = nt * 16;
                f32x4 acc = {0.f, 0.f, 0.f, 0.f};
                acc = __builtin_amdgcn_mfma_f32_16x16x32_bf16(a0, ldB(WxT, 128, n0, lr, lq, 0),  acc, 0, 0, 0);
                acc = __builtin_amdgcn_mfma_f32_16x16x32_bf16(a1, ldB(WxT, 128, n0, lr, lq, 32), acc, 0, 0, 0);
                acc = __builtin_amdgcn_mfma_f32_16x16x32_bf16(a2, ldB(WxT, 128, n0, lr, lq, 64), acc, 0, 0, 0);
                acc = __builtin_amdgcn_mfma_f32_16x16x32_bf16(a3, ldB(WxT, 128, n0, lr, lq, 96), acc, 0, 0, 0);
                const float bv = bx[n0 + lr];
                const unsigned short h0 = f2bf(sigmoid_f(acc[0] + bv));
                const unsigned short h1 = f2bf(sigmoid_f(acc[1] + bv));
                const unsigned short h2 = f2bf(sigmoid_f(acc[2] + bv));
                const unsigned short h3 = f2bf(sigmoid_f(acc[3] + bv));
                gxp[nt * 2]     = (unsigned)h0 | ((unsigned)h1 << 16);
                gxp[nt * 2 + 1] = (unsigned)h2 | ((unsigned)h3 << 16);
            }
        }

        // ---- dense chain (wave-local ping-pong) ----
        denseL<7, 4>(W1T, 128, b1, 100, sX, sA, mbase, lr, lq);   // L1: sX -> sA
        denseL<7, 4>(W2T, 128, b2, 100, sA, sX, mbase, lr, lq);   // L2: sA -> sX
        {   // zero sX cols 112..127 (x leftovers) before L3's K=128 read of sX
            uint2 z = {0u, 0u};
            *reinterpret_cast<uint2*>(&sX[(mbase + lr) * LDSX + 112 + lq * 4]) = z;
        }
        denseL<7, 4>(W3T, 128, b3, 100, sX, sA, mbase, lr, lq);   // L3: sX -> sA
        denseL<4, 4>(W4T, 128, b4,  50, sA, sX, mbase, lr, lq);   // L4: sA -> sX (cols 0..63)

        // ---- L5 (50->256, K=64) fused with gate + scatter ----
        {
            short8 a0 = ldsA(sX, mbase, lr, lq, 0), a1 = ldsA(sX, mbase, lr, lq, 32);
            #pragma unroll 4
            for (int nt = 0; nt < 16; ++nt) {
                const int n0 = nt * 16;
                f32x4 acc = {0.f, 0.f, 0.f, 0.f};
                acc = __builtin_amdgcn_mfma_f32_16x16x32_bf16(a0, ldB(W5T, 64, n0, lr, lq, 0),  acc, 0, 0, 0);
                acc = __builtin_amdgcn_mfma_f32_16x16x32_bf16(a1, ldB(W5T, 64, n0, lr, lq, 32), acc, 0, 0, 0);
                const float bv = b5[n0 + lr];
                const unsigned u0 = gxp[nt * 2], u1 = gxp[nt * 2 + 1];
                const float gxv[4] = { bf2f((unsigned short)(u0 & 0xffff)),
                                       bf2f((unsigned short)(u0 >> 16)),
                                       bf2f((unsigned short)(u1 & 0xffff)),
                                       bf2f((unsigned short)(u1 >> 16)) };
                #pragma unroll
                for (int r = 0; r < 4; ++r) {
                    const int t = tw0 + lq * 4 + r;
                    const float g = sigmoid_f(acc[r] + bv) * gxv[r];
                    int v = n0 + lr + s * (T_N - 1 - t);
                    v %= H_N; if (v < 0) v += H_N;
                    atomicAdd(&accum[v], g);   // per-t the h-map is a bijection
                }
            }
        }
    }

    __syncthreads();
    // flush partial hidden (4 segment-blocks per b -> global atomic, out zeroed)
    atomicAdd(&out[256 + b * 256 + tid], accum[tid]);
}

// output[b] = sigmoid(hidden[b,:] @ Wo + bo)
__global__ __launch_bounds__(256) void srnn_output(
    const float* __restrict__ Wo, const float* __restrict__ bo,
    float* __restrict__ out)
{
    __shared__ float red[256];
    const int b = blockIdx.x, tid = threadIdx.x;
    red[tid] = out[256 + b * 256 + tid] * Wo[tid];
    __syncthreads();
    #pragma unroll
    for (int off = 128; off > 0; off >>= 1) {
        if (tid < off) red[tid] += red[tid + off];
        __syncthreads();
    }
    if (tid == 0) out[b] = sigmoid_f(red[0] + bo[0]);
}

extern "C" void kernel_launch(void* const* d_in, const int* in_sizes, int n_in,
                              void* d_out, int out_size, void* d_ws, size_t ws_size,
                              hipStream_t stream)
{
    const float* x  = (const float*)d_in[0];
    const float* Wx = (const float*)d_in[1];
    const float* bx = (const float*)d_in[2];
    const float* W1 = (const float*)d_in[3];
    const float* b1 = (const float*)d_in[4];
    const float* W2 = (const float*)d_in[5];
    const float* b2 = (const float*)d_in[6];
    const float* W3 = (const float*)d_in[7];
    const float* b3 = (const float*)d_in[8];
    const float* W4 = (const float*)d_in[9];
    const float* b4 = (const float*)d_in[10];
    const float* W5 = (const float*)d_in[11];
    const float* b5 = (const float*)d_in[12];
    const float* Wo = (const float*)d_in[13];
    const float* bo = (const float*)d_in[14];
    const int* shiftp = (const int*)d_in[15];
    float* out = (float*)d_out;
    short* wt  = (short*)d_ws;   // 200,704 B of scratch for bf16 transposed weights

    // hidden accumulated with atomics -> zero-init (d_out is poisoned)
    hipMemsetAsync(d_out, 0, (size_t)out_size * sizeof(float), stream);

    prep_weights<<<dim3((WT_TOTAL + 255) / 256), dim3(256), 0, stream>>>(
        Wx, W1, W2, W3, W4, W5, wt);
    srnn_gate_scan<<<dim3(1024), dim3(256), 0, stream>>>(
        x, wt, bx, b1, b2, b3, b4, b5, shiftp, out);
    srnn_output<<<dim3(256), dim3(256), 0, stream>>>(Wo, bo, out);
}